// Round 6
// baseline (181671.497 us; speedup 1.0000x reference)
//
#include <hip/hip_runtime.h>
#include <hip/hip_bf16.h>

typedef __hip_bfloat16 bf16;

#define NB   32
#define TE   600
#define TD   600
#define TGT  80
#define PREN 256
#define HID  512
#define ATTD 128
#define LF   32
#define LK   31
#define PH   512

__device__ __forceinline__ float b2f(bf16 x){ return __bfloat162float(x); }

__device__ __forceinline__ void ld8bf(const bf16* p, float* o){
  const uint4 u = *(const uint4*)p;
  o[0]=__uint_as_float(u.x<<16); o[1]=__uint_as_float(u.x&0xFFFF0000u);
  o[2]=__uint_as_float(u.y<<16); o[3]=__uint_as_float(u.y&0xFFFF0000u);
  o[4]=__uint_as_float(u.z<<16); o[5]=__uint_as_float(u.z&0xFFFF0000u);
  o[6]=__uint_as_float(u.w<<16); o[7]=__uint_as_float(u.w&0xFFFF0000u);
}

__device__ __forceinline__ void ld8f(const float* p, float* o){
  float4 a=*(const float4*)p, b=*(const float4*)(p+4);
  o[0]=a.x;o[1]=a.y;o[2]=a.z;o[3]=a.w;
  o[4]=b.x;o[5]=b.y;o[6]=b.z;o[7]=b.w;
}

__device__ __forceinline__ float dot8(const float* w, const float* z){
  return w[0]*z[0]+w[1]*z[1]+w[2]*z[2]+w[3]*z[3]
       + w[4]*z[4]+w[5]*z[5]+w[6]*z[6]+w[7]*z[7];
}

__device__ __forceinline__ float sigm(float x){ return 1.f/(1.f+__expf(-x)); }
__device__ __forceinline__ float tanhfast(float x){
  float e = __expf(2.f*x);
  return 1.f - 2.f/(e+1.f);
}

// ---- hand-rolled grid barrier (device-scope; all 256 blocks co-resident) ----
__device__ __forceinline__ void gbar(int* cnt, int target){
  __syncthreads();
  if (threadIdx.x==0){
    __threadfence();                       // release prior writes
    atomicAdd(cnt, 1);                     // device-scope arrive
    while (__hip_atomic_load(cnt, __ATOMIC_ACQUIRE, __HIP_MEMORY_SCOPE_AGENT) < target)
      __builtin_amdgcn_s_sleep(1);
  }
  __syncthreads();
  __threadfence();                         // acquire for all threads
}

// ---------------- prenet: XS[t][b][256] (bf16) -----------------
__global__ __launch_bounds__(256) void k_prenet(const float* __restrict__ dec,
    const float* __restrict__ w1, const float* __restrict__ b1,
    const float* __restrict__ w2, const float* __restrict__ b2,
    bf16* __restrict__ XS)
{
  int t = blockIdx.x, tid = threadIdx.x;
  __shared__ __align__(16) float fr[NB*TGT];
  __shared__ __align__(16) float h1[NB*PREN];
  for (int i=tid;i<NB*TGT;i+=256){
    int b=i/TGT,c=i%TGT;
    fr[b*TGT+c] = (t==0)?0.f:dec[((size_t)b*TD+(t-1))*TGT+c];
  }
  __syncthreads();
  {
    int oc=tid; float bb=b1[oc];
    const float* wr = w1 + (size_t)oc*TGT;
    for (int b=0;b<NB;b++){
      float acc=bb;
      for (int k=0;k<TGT;k+=8){
        float wv[8]; ld8f(wr+k,wv);
        acc += dot8(wv, fr + b*TGT + k);
      }
      h1[b*PREN+oc]=fmaxf(acc,0.f);
    }
  }
  __syncthreads();
  {
    int oc=tid; float bb=b2[oc];
    const float* wr = w2 + (size_t)oc*PREN;
    for (int b=0;b<NB;b++){
      float acc=bb;
      for (int k=0;k<PREN;k+=8){
        float wv[8]; ld8f(wr+k,wv);
        acc += dot8(wv, h1 + b*PREN + k);
      }
      XS[((size_t)t*NB+b)*PREN+oc]=__float2bfloat16(fmaxf(acc,0.f));
    }
  }
}

// ---------------- proc_mem: PM[b][t][128] (bf16) -----------------
__global__ __launch_bounds__(256) void k_procmem(const float* __restrict__ enc,
    const float* __restrict__ mw, const float* __restrict__ mb, bf16* __restrict__ PM)
{
  int t=blockIdx.x, tid=threadIdx.x;
  __shared__ __align__(16) float xe[16*HID];
  int a = tid & 127, bh = tid >> 7;
  float bb = mb[a];
  const float* wr = mw + (size_t)a*HID;
  for (int half=0; half<2; half++){
    __syncthreads();
    for (int i=tid;i<16*HID;i+=256){
      int bl=i>>9, h=i&511;
      xe[i] = enc[((size_t)(half*16+bl)*TE + t)*HID + h];
    }
    __syncthreads();
    for (int bl=bh*8; bl<bh*8+8; bl++){
      float acc=bb;
      for (int k=0;k<HID;k+=8){
        float wv[8]; ld8f(wr+k,wv);
        acc += dot8(wv, xe + bl*HID + k);
      }
      PM[((size_t)(half*16+bl)*TE + t)*ATTD + a] = __float2bfloat16(acc);
    }
  }
}

// ================ persistent scan kernel (manual grid barrier) ================
// grid 256 x block 256.  3 gbar per step.
__global__ __launch_bounds__(256) void k_scan(
    const bf16* __restrict__ XS, const bf16* __restrict__ PM,
    const float* __restrict__ enc, float* __restrict__ MEL,
    float* __restrict__ AH0, float* __restrict__ AH1, float* __restrict__ AC,
    float* __restrict__ DH0, float* __restrict__ DH1, float* __restrict__ DC,
    float* __restrict__ CTX0, float* __restrict__ CTX1,
    float* __restrict__ W, float* __restrict__ WC, float* __restrict__ E,
    int* __restrict__ barcnt,
    const float* __restrict__ awih, const float* __restrict__ awhh,
    const float* __restrict__ abih, const float* __restrict__ abhh,
    const float* __restrict__ dwih, const float* __restrict__ dwhh,
    const float* __restrict__ dbih, const float* __restrict__ dbhh,
    const float* __restrict__ qw, const float* __restrict__ convw,
    const float* __restrict__ fcw, const float* __restrict__ vw,
    const float* __restrict__ projw)
{
  const int bid = blockIdx.x, tid = threadIdx.x;
  const int b = bid>>3, chunk = bid&7;   // phase B/C roles
  int nbar = 0;

  // ---- persistent LDS (loaded once) ----
  __shared__ __align__(16) float fcs[128*33];
  __shared__ __align__(16) float cw0[32*31], cw1[32*31];
  __shared__ float vv[128];
  // ---- per-step LDS ----
  __shared__ __align__(16) float wpad[632], wcpad[632];
  __shared__ float qs[128];
  __shared__ float convb[4][32];
  __shared__ __align__(16) float wl[600];
  __shared__ float ctxp[64][9];
  __shared__ float melp[10][16];
  __shared__ float red[4];
  __shared__ float sbc;

  for (int i=tid;i<128*33;i+=256){ int a=i/33,c=i-a*33; fcs[i]=(c<32)?fcw[a*32+c]:0.f; }
  for (int i=tid;i<32*31;i+=256){ int c=i/31,k=i-c*31; cw0[i]=convw[c*62+k]; cw1[i]=convw[c*62+31+k]; }
  if (tid<128) vv[tid]=vw[tid];
  __syncthreads();

  float* AHb[2]={AH0,AH1};
  float* DHb[2]={DH0,DH1};
  float* CTXb[2]={CTX0,CTX1};

  for (int t=0;t<=TD;t++){
    const int p=t&1, pp=1-p;
    const float* AHr = AHb[pp];  float* AHw = AHb[p];
    const float* CTXr= CTXb[pp]; float* CTXw= CTXb[p];

    // ================= phase A: lstmA(t) || lstmD(t-1) =================
    if (bid < 128){
      if (t < TD){
        const int ba=tid>>3, j=tid&7, c0=bid*4;
        const bf16* xs = XS + ((size_t)t*NB+ba)*PREN;
        const float* cx = CTXr + ba*HID;
        const float* hr = AHr + ba*HID;
        float acc[16];
        #pragma unroll
        for (int q=0;q<16;q++) acc[q]=0.f;
        for (int i=0;i<20;i++){
          int k8=i*64+j*8;
          float z[8];
          if (k8<256) ld8bf(xs+k8,z);
          else ld8f((k8<768)? cx+(k8-256) : hr+(k8-768), z);
          #pragma unroll
          for (int cc=0;cc<4;cc++){
            #pragma unroll
            for (int g=0;g<4;g++){
              int row=g*HID+c0+cc;
              const float* wp=(k8<768)? awih+(size_t)row*768+k8
                                      : awhh+(size_t)row*HID+(k8-768);
              float wv[8]; ld8f(wp,wv);
              acc[cc*4+g]+=dot8(wv,z);
            }
          }
        }
        #pragma unroll
        for (int q=0;q<16;q++){
          acc[q]+=__shfl_xor(acc[q],1);
          acc[q]+=__shfl_xor(acc[q],2);
          acc[q]+=__shfl_xor(acc[q],4);
        }
        if (j==0){
          #pragma unroll
          for (int cc=0;cc<4;cc++){
            int cell=c0+cc;
            float g0=acc[cc*4+0]+abih[cell]+abhh[cell];
            float g1=acc[cc*4+1]+abih[HID+cell]+abhh[HID+cell];
            float g2=acc[cc*4+2]+abih[2*HID+cell]+abhh[2*HID+cell];
            float g3=acc[cc*4+3]+abih[3*HID+cell]+abhh[3*HID+cell];
            float c2=sigm(g1)*AC[ba*HID+cell]+sigm(g0)*tanhfast(g2);
            AC[ba*HID+cell]=c2;
            AHw[ba*HID+cell]=sigm(g3)*tanhfast(c2);
          }
        }
      }
    } else if (t>=1){
      const int ba=tid>>3, j=tid&7, c0=(bid-128)*4;
      const float* ah = AHr + ba*HID;      // AH(t-1)
      const float* cx = CTXr + ba*HID;     // CTX(t-1)
      const float* dhr= DHb[p] + ba*HID;   // DH(t-2)
      float* DHw = DHb[pp];                // DH(t-1)
      float acc[16];
      #pragma unroll
      for (int q=0;q<16;q++) acc[q]=0.f;
      for (int i=0;i<24;i++){
        int k8=i*64+j*8;
        float z[8];
        ld8f((k8<512)? ah+k8 : (k8<1024)? cx+(k8-512) : dhr+(k8-1024), z);
        #pragma unroll
        for (int cc=0;cc<4;cc++){
          #pragma unroll
          for (int g=0;g<4;g++){
            int row=g*HID+c0+cc;
            const float* wp=(k8<1024)? dwih+(size_t)row*1024+k8
                                     : dwhh+(size_t)row*HID+(k8-1024);
            float wv[8]; ld8f(wp,wv);
            acc[cc*4+g]+=dot8(wv,z);
          }
        }
      }
      #pragma unroll
      for (int q=0;q<16;q++){
        acc[q]+=__shfl_xor(acc[q],1);
        acc[q]+=__shfl_xor(acc[q],2);
        acc[q]+=__shfl_xor(acc[q],4);
      }
      if (j==0){
        #pragma unroll
        for (int cc=0;cc<4;cc++){
          int cell=c0+cc;
          float g0=acc[cc*4+0]+dbih[cell]+dbhh[cell];
          float g1=acc[cc*4+1]+dbih[HID+cell]+dbhh[HID+cell];
          float g2=acc[cc*4+2]+dbih[2*HID+cell]+dbhh[2*HID+cell];
          float g3=acc[cc*4+3]+dbih[3*HID+cell]+dbhh[3*HID+cell];
          float c2=sigm(g1)*DC[ba*HID+cell]+sigm(g0)*tanhfast(g2);
          DC[ba*HID+cell]=c2;
          DHw[ba*HID+cell]=sigm(g3)*tanhfast(c2);
        }
      }
    }
    nbar++; gbar(barcnt, 256*nbar);

    // ================= phase B: mel(t-1) + q(t) + energies(t) ==========
    if (t>=1 && tid<160){
      int ol=tid>>4, ks=tid&15, k0=ks*64;
      const float* dh = DHb[pp] + b*HID;   // DH(t-1)
      const float* cx = CTXr + b*HID;      // CTX(t-1)
      const float* zp = (k0<512)? dh+k0 : cx+(k0-512);
      const float* pw = projw + (size_t)(chunk*10+ol)*1024 + k0;
      float a=0.f;
      #pragma unroll
      for (int k=0;k<64;k+=8){
        float wv[8],z[8]; ld8f(pw+k,wv); ld8f(zp+k,z);
        a+=dot8(wv,z);
      }
      melp[ol][ks]=a;
    }
    if (t<TD){
      if (tid<128){
        const float* qr=qw+(size_t)tid*HID;
        const float* ah=AHw + b*HID;       // AH(t)
        float acc=0.f;
        for (int k=0;k<HID;k+=8){
          float wv[8]; ld8f(qr+k,wv);
          acc += dot8(wv, ah+k);
        }
        qs[tid]=acc;
      }
      for (int i=tid;i<630;i+=256){
        wpad[i]  = (i>=15&&i<615)? W [(size_t)b*TE+i-15] : 0.f;
        wcpad[i] = (i>=15&&i<615)? WC[(size_t)b*TE+i-15] : 0.f;
      }
    }
    __syncthreads();
    if (t>=1 && tid<10){
      float s=0.f;
      #pragma unroll
      for (int k=0;k<16;k++) s+=melp[tid][k];
      MEL[((size_t)b*TD+(t-1))*TGT+chunk*10+tid]=s;
    }
    if (t==TD) break;   // after lstmD(599) + mel(599)
    {
      int wid=tid>>6, lane=tid&63, tbase=chunk*75;
      for (int it=0; it<19; it++){
        int off=it*4+wid; int te=tbase+off; bool act=(off<75);
        if (act&&lane<32){
          float s=0.f; int c=lane;
          for (int k=0;k<LK;k++)
            s+=cw0[c*31+k]*wpad[te+k]+cw1[c*31+k]*wcpad[te+k];
          convb[wid][c]=s;
        }
        __syncthreads();
        if (act){
          float part=0.f;
          #pragma unroll
          for (int half=0;half<2;half++){
            int a=lane+half*64;
            float loc=0.f;
            #pragma unroll
            for (int c=0;c<32;c++) loc+=fcs[a*33+c]*convb[wid][c];
            float x=qs[a]+b2f(PM[((size_t)b*TE+te)*ATTD+a])+loc;
            part+=vv[a]*tanhfast(x);
          }
          for (int o2=1;o2<64;o2<<=1) part+=__shfl_xor(part,o2);
          if (lane==0) E[(size_t)b*TE+te]=part;
        }
        __syncthreads();
      }
    }
    nbar++; gbar(barcnt, 256*nbar);

    // ================= phase C: softmax(b) + ctx slice =================
    {
      const int hc=chunk;
      float e0[3]; float mx=-1e30f;
      #pragma unroll
      for (int r=0;r<3;r++){
        int i=tid+r*256;
        float v=(i<TE)? E[(size_t)b*TE+i] : -1e30f;
        e0[r]=v; mx=fmaxf(mx,v);
      }
      for (int o2=1;o2<64;o2<<=1) mx=fmaxf(mx,__shfl_xor(mx,o2));
      if ((tid&63)==0) red[tid>>6]=mx;
      __syncthreads();
      if (tid==0) sbc=fmaxf(fmaxf(red[0],red[1]),fmaxf(red[2],red[3]));
      __syncthreads();
      float m=sbc;
      float ex[3], s=0.f;
      #pragma unroll
      for (int r=0;r<3;r++){
        int i=tid+r*256;
        ex[r]=(i<TE)? __expf(e0[r]-m) : 0.f;
        s+=ex[r];
      }
      for (int o2=1;o2<64;o2<<=1) s+=__shfl_xor(s,o2);
      __syncthreads();
      if ((tid&63)==0) red[tid>>6]=s;
      __syncthreads();
      if (tid==0) sbc=red[0]+red[1]+red[2]+red[3];
      __syncthreads();
      float inv=1.f/sbc;
      #pragma unroll
      for (int r=0;r<3;r++){
        int i=tid+r*256;
        if (i<TE){
          float w2=ex[r]*inv;
          wl[i]=w2;
          if (hc==0){ W[(size_t)b*TE+i]=w2; WC[(size_t)b*TE+i]+=w2; }
        }
      }
      __syncthreads();
      int hl2=tid&31, ts=tid>>5;
      int h=hc*64+hl2*2;
      const float* ep = enc + (size_t)b*TE*HID + h;
      float a0=0.f,a1=0.f;
      for (int tt=ts*75; tt<ts*75+75; tt++){
        float2 u=*(const float2*)(ep+(size_t)tt*HID);
        float w2=wl[tt]; a0+=w2*u.x; a1+=w2*u.y;
      }
      ctxp[hl2*2][ts]=a0; ctxp[hl2*2+1][ts]=a1;
      __syncthreads();
      if (tid<64){
        float s2=0.f;
        #pragma unroll
        for (int k=0;k<8;k++) s2+=ctxp[tid][k];
        CTXw[(size_t)b*HID+hc*64+tid]=s2;
      }
    }
    nbar++; gbar(barcnt, 256*nbar);
  }
}

// ---------------- postnet conv (generic, bf16 internal activations) --------
__global__ __launch_bounds__(256) void k_conv(
    const void* __restrict__ inv_, bf16* __restrict__ out,
    const float* __restrict__ w, const float* __restrict__ bias,
    int IC, int OC, int mel_in, int do_tanh, int b0)
{
  __shared__ __align__(16) float xs[256*36];
  int bl=blockIdx.x, bg=b0+bl, oct=blockIdx.y, t0=blockIdx.z*32, tid=threadIdx.x;
  int oc = oct*256 + tid;
  float acc[32];
  #pragma unroll
  for (int q=0;q<32;q++) acc[q]=0.f;
  int nch=(IC+255)/256;
  const float* inf_ = (const float*)inv_;
  const bf16*  inb_ = (const bf16*)inv_;
  for (int ch=0;ch<nch;ch++){
    int icb=ch*256, icn=min(256,IC-icb);
    __syncthreads();
    for (int i=tid;i<icn*36;i+=256){
      int icl=i/36, tt=i-icl*36;
      int tg=t0+tt-2;
      float v=0.f;
      if (tg>=0 && tg<TD){
        int ic=icb+icl;
        v = mel_in ? inf_[((size_t)bg*TD+tg)*TGT+ic]
                   : b2f(inb_[((size_t)bl*IC+ic)*TD+tg]);
      }
      xs[i]=v;
    }
    __syncthreads();
    if (oc<OC){
      const float* wp = w + ((size_t)oc*IC+icb)*5;
      for (int ic=0;ic<icn;ic++){
        float xw[36];
        #pragma unroll
        for (int q=0;q<9;q++) ((float4*)xw)[q]=((const float4*)(xs+ic*36))[q];
        float wk0=wp[ic*5  ],wk1=wp[ic*5+1],wk2=wp[ic*5+2],
              wk3=wp[ic*5+3],wk4=wp[ic*5+4];
        #pragma unroll
        for (int tt=0;tt<32;tt++)
          acc[tt] += wk0*xw[tt]+wk1*xw[tt+1]+wk2*xw[tt+2]+wk3*xw[tt+3]+wk4*xw[tt+4];
      }
    }
  }
  if (oc<OC){
    float bv=bias[oc];
    for (int tt=0;tt<32;tt++){
      int tg=t0+tt;
      if (tg<TD){
        float v=acc[tt]+bv;
        if (do_tanh) v=tanhfast(v);
        out[((size_t)bl*OC+oc)*TD+tg]=__float2bfloat16(v);
      }
    }
  }
}

// ---------------- postnet last layer + in-place residual on d_out ----------
__global__ __launch_bounds__(256) void k_conv_last(
    const bf16* __restrict__ in, const float* __restrict__ w,
    const float* __restrict__ bias, float* __restrict__ outp, int b0)
{
  __shared__ __align__(16) float xs[256*36];
  int bl=blockIdx.x, bg=b0+bl, t0=blockIdx.z*32, tid=threadIdx.x;
  int oc = tid;
  float acc[32];
  #pragma unroll
  for (int q=0;q<32;q++) acc[q]=0.f;
  for (int ch=0;ch<2;ch++){
    int icb=ch*256;
    __syncthreads();
    for (int i=tid;i<256*36;i+=256){
      int icl=i/36, tt=i-icl*36;
      int tg=t0+tt-2;
      float v=0.f;
      if (tg>=0 && tg<TD){
        int ic=icb+icl;
        v = b2f(in[((size_t)bl*PH+ic)*TD+tg]);
      }
      xs[i]=v;
    }
    __syncthreads();
    if (oc<TGT){
      const float* wp = w + ((size_t)oc*PH+icb)*5;
      for (int ic=0;ic<256;ic++){
        float xw[36];
        #pragma unroll
        for (int q=0;q<9;q++) ((float4*)xw)[q]=((const float4*)(xs+ic*36))[q];
        float wk0=wp[ic*5  ],wk1=wp[ic*5+1],wk2=wp[ic*5+2],
              wk3=wp[ic*5+3],wk4=wp[ic*5+4];
        #pragma unroll
        for (int tt=0;tt<32;tt++)
          acc[tt] += wk0*xw[tt]+wk1*xw[tt+1]+wk2*xw[tt+2]+wk3*xw[tt+3]+wk4*xw[tt+4];
      }
    }
  }
  if (oc<TGT){
    float bv=bias[oc];
    for (int tt=0;tt<32;tt++){
      int tg=t0+tt;
      if (tg<TD){
        size_t idx=((size_t)bg*TD+tg)*TGT+oc;
        outp[idx]=acc[tt]+bv+outp[idx];
      }
    }
  }
}

extern "C" void kernel_launch(void* const* d_in, const int* in_sizes, int n_in,
                              void* d_out, int out_size, void* d_ws, size_t ws_size,
                              hipStream_t stream)
{
  const float* enc =(const float*)d_in[0];
  const float* dec =(const float*)d_in[1];
  const float* pw1 =(const float*)d_in[2];  const float* pb1=(const float*)d_in[3];
  const float* pw2 =(const float*)d_in[4];  const float* pb2=(const float*)d_in[5];
  const float* awih=(const float*)d_in[6];  const float* awhh=(const float*)d_in[7];
  const float* abih=(const float*)d_in[8];  const float* abhh=(const float*)d_in[9];
  const float* dwih=(const float*)d_in[10]; const float* dwhh=(const float*)d_in[11];
  const float* dbih=(const float*)d_in[12]; const float* dbhh=(const float*)d_in[13];
  const float* memw=(const float*)d_in[14]; const float* memb=(const float*)d_in[15];
  const float* qw  =(const float*)d_in[16];
  const float* lcw =(const float*)d_in[17];
  const float* lfw =(const float*)d_in[18];
  const float* vw  =(const float*)d_in[19];
  const float* pjw =(const float*)d_in[20];
  const float* cwt0=(const float*)d_in[21]; const float* cbt0=(const float*)d_in[22];
  const float* cwt1=(const float*)d_in[23]; const float* cbt1=(const float*)d_in[24];
  const float* cwt2=(const float*)d_in[25]; const float* cbt2=(const float*)d_in[26];
  const float* cwt3=(const float*)d_in[27]; const float* cbt3=(const float*)d_in[28];
  const float* cwt4=(const float*)d_in[29]; const float* cbt4=(const float*)d_in[30];
  float* MEL = (float*)d_out;
  (void)in_sizes; (void)n_in; (void)out_size; (void)ws_size;

  char* base=(char*)d_ws;
  const size_t XS_B = (size_t)TD*NB*PREN*2;   //  9,830,400 B
  const size_t PM_B = (size_t)NB*TE*ATTD*2;   //  4,915,200 B
  const size_t HB   = (size_t)NB*HID*4;       //     65,536 B
  const size_t WB   = (size_t)NB*TE*4;        //     76,800 B
  bf16* XSb = (bf16*)base;
  bf16* PMb = (bf16*)(base + XS_B);
  char* sbase = base + XS_B + PM_B;
  float* AH0 =(float*)(sbase+0*HB);
  float* AH1 =(float*)(sbase+1*HB);
  float* ACb =(float*)(sbase+2*HB);
  float* DH0 =(float*)(sbase+3*HB);
  float* DH1 =(float*)(sbase+4*HB);
  float* DCb =(float*)(sbase+5*HB);
  float* CTX0=(float*)(sbase+6*HB);
  float* CTX1=(float*)(sbase+7*HB);
  float* Wb  =(float*)(sbase+8*HB);
  float* WCb =(float*)(sbase+8*HB+WB);
  float* Eb  =(float*)(sbase+8*HB+2*WB);
  int*   barcnt=(int*)(sbase+8*HB+3*WB);
  const int G = 8;
  const size_t PBc_B = (size_t)G*PH*TD*2;     //  4,915,200 B
  bf16* PB0 = (bf16*)base;
  bf16* PB1 = (bf16*)(base + PBc_B);

  hipMemsetAsync(sbase, 0, 8*HB+3*WB+256, stream);

  k_prenet<<<TD,256,0,stream>>>(dec,pw1,pb1,pw2,pb2,XSb);
  k_procmem<<<TE,256,0,stream>>>(enc,memw,memb,PMb);

  k_scan<<<256,256,0,stream>>>(XSb,PMb,enc,MEL,
      AH0,AH1,ACb,DH0,DH1,DCb,CTX0,CTX1,Wb,WCb,Eb,barcnt,
      awih,awhh,abih,abhh,dwih,dwhh,dbih,dbhh,
      qw,lcw,lfw,vw,pjw);

  for (int c=0;c<NB/G;c++){
    int b0=c*G;
    k_conv<<<dim3(G,2,19),256,0,stream>>>(MEL,PB0,cwt0,cbt0,TGT,PH,1,1,b0);
    k_conv<<<dim3(G,2,19),256,0,stream>>>(PB0,PB1,cwt1,cbt1,PH,PH,0,1,b0);
    k_conv<<<dim3(G,2,19),256,0,stream>>>(PB1,PB0,cwt2,cbt2,PH,PH,0,1,b0);
    k_conv<<<dim3(G,2,19),256,0,stream>>>(PB0,PB1,cwt3,cbt3,PH,PH,0,1,b0);
    k_conv_last<<<dim3(G,1,19),256,0,stream>>>(PB1,cwt4,cbt4,MEL,b0);
  }
}

// Round 7
// 113441.321 us; speedup vs baseline: 1.6015x; 1.6015x over previous
//
#include <hip/hip_runtime.h>
#include <hip/hip_bf16.h>

typedef __hip_bfloat16 bf16;

#define NB   32
#define TE   600
#define TD   600
#define TGT  80
#define PREN 256
#define HID  512
#define ATTD 128
#define LF   32
#define LK   31
#define PH   512

__device__ __forceinline__ float b2f(bf16 x){ return __bfloat162float(x); }

__device__ __forceinline__ void ld8bf(const bf16* p, float* o){
  const uint4 u = *(const uint4*)p;
  o[0]=__uint_as_float(u.x<<16); o[1]=__uint_as_float(u.x&0xFFFF0000u);
  o[2]=__uint_as_float(u.y<<16); o[3]=__uint_as_float(u.y&0xFFFF0000u);
  o[4]=__uint_as_float(u.z<<16); o[5]=__uint_as_float(u.z&0xFFFF0000u);
  o[6]=__uint_as_float(u.w<<16); o[7]=__uint_as_float(u.w&0xFFFF0000u);
}

__device__ __forceinline__ void ld8f(const float* p, float* o){
  float4 a=*(const float4*)p, b=*(const float4*)(p+4);
  o[0]=a.x;o[1]=a.y;o[2]=a.z;o[3]=a.w;
  o[4]=b.x;o[5]=b.y;o[6]=b.z;o[7]=b.w;
}

__device__ __forceinline__ float dot8(const float* w, const float* z){
  return w[0]*z[0]+w[1]*z[1]+w[2]*z[2]+w[3]*z[3]
       + w[4]*z[4]+w[5]*z[5]+w[6]*z[6]+w[7]*z[7];
}

__device__ __forceinline__ float sigm(float x){ return 1.f/(1.f+__expf(-x)); }
__device__ __forceinline__ float tanhfast(float x){
  float e = __expf(2.f*x);
  return 1.f - 2.f/(e+1.f);
}

// ---- low-contention grid barrier: per-block arrive slots + master broadcast ----
// arrive[bid*16]: padded slots (relaxed agent stores, no RMW contention)
// block 0 / wave 0 polls all slots in parallel, then broadcasts via go-flag.
__device__ __forceinline__ void gbar(int* arrive, int* go, int nbar){
  __syncthreads();
  if (threadIdx.x==0){
    __builtin_amdgcn_fence(__ATOMIC_RELEASE, "agent");   // one L2 writeback per block
    __hip_atomic_store(&arrive[blockIdx.x*16], nbar,
                       __ATOMIC_RELAXED, __HIP_MEMORY_SCOPE_AGENT);
  }
  if (blockIdx.x==0){
    if (threadIdx.x<64){
      for(;;){
        int m0=__hip_atomic_load(&arrive[(threadIdx.x*4+0)*16],__ATOMIC_RELAXED,__HIP_MEMORY_SCOPE_AGENT);
        int m1=__hip_atomic_load(&arrive[(threadIdx.x*4+1)*16],__ATOMIC_RELAXED,__HIP_MEMORY_SCOPE_AGENT);
        int m2=__hip_atomic_load(&arrive[(threadIdx.x*4+2)*16],__ATOMIC_RELAXED,__HIP_MEMORY_SCOPE_AGENT);
        int m3=__hip_atomic_load(&arrive[(threadIdx.x*4+3)*16],__ATOMIC_RELAXED,__HIP_MEMORY_SCOPE_AGENT);
        int m=min(min(m0,m1),min(m2,m3));
        if (__all(m>=nbar)) break;
        __builtin_amdgcn_s_sleep(4);
      }
      if (threadIdx.x==0)
        __hip_atomic_store(go, nbar, __ATOMIC_RELAXED, __HIP_MEMORY_SCOPE_AGENT);
    }
  } else if (threadIdx.x==0){
    while (__hip_atomic_load(go, __ATOMIC_RELAXED, __HIP_MEMORY_SCOPE_AGENT) < nbar)
      __builtin_amdgcn_s_sleep(4);
  }
  __syncthreads();
  __builtin_amdgcn_fence(__ATOMIC_ACQUIRE, "agent");     // L1 invalidate only
}

// ---------------- prenet: XS[t][b][256] (bf16) -----------------
__global__ __launch_bounds__(256) void k_prenet(const float* __restrict__ dec,
    const float* __restrict__ w1, const float* __restrict__ b1,
    const float* __restrict__ w2, const float* __restrict__ b2,
    bf16* __restrict__ XS)
{
  int t = blockIdx.x, tid = threadIdx.x;
  __shared__ __align__(16) float fr[NB*TGT];
  __shared__ __align__(16) float h1[NB*PREN];
  for (int i=tid;i<NB*TGT;i+=256){
    int b=i/TGT,c=i%TGT;
    fr[b*TGT+c] = (t==0)?0.f:dec[((size_t)b*TD+(t-1))*TGT+c];
  }
  __syncthreads();
  {
    int oc=tid; float bb=b1[oc];
    const float* wr = w1 + (size_t)oc*TGT;
    for (int b=0;b<NB;b++){
      float acc=bb;
      for (int k=0;k<TGT;k+=8){
        float wv[8]; ld8f(wr+k,wv);
        acc += dot8(wv, fr + b*TGT + k);
      }
      h1[b*PREN+oc]=fmaxf(acc,0.f);
    }
  }
  __syncthreads();
  {
    int oc=tid; float bb=b2[oc];
    const float* wr = w2 + (size_t)oc*PREN;
    for (int b=0;b<NB;b++){
      float acc=bb;
      for (int k=0;k<PREN;k+=8){
        float wv[8]; ld8f(wr+k,wv);
        acc += dot8(wv, h1 + b*PREN + k);
      }
      XS[((size_t)t*NB+b)*PREN+oc]=__float2bfloat16(fmaxf(acc,0.f));
    }
  }
}

// ---------------- proc_mem: PM[b][t][128] (bf16) -----------------
__global__ __launch_bounds__(256) void k_procmem(const float* __restrict__ enc,
    const float* __restrict__ mw, const float* __restrict__ mb, bf16* __restrict__ PM)
{
  int t=blockIdx.x, tid=threadIdx.x;
  __shared__ __align__(16) float xe[16*HID];
  int a = tid & 127, bh = tid >> 7;
  float bb = mb[a];
  const float* wr = mw + (size_t)a*HID;
  for (int half=0; half<2; half++){
    __syncthreads();
    for (int i=tid;i<16*HID;i+=256){
      int bl=i>>9, h=i&511;
      xe[i] = enc[((size_t)(half*16+bl)*TE + t)*HID + h];
    }
    __syncthreads();
    for (int bl=bh*8; bl<bh*8+8; bl++){
      float acc=bb;
      for (int k=0;k<HID;k+=8){
        float wv[8]; ld8f(wr+k,wv);
        acc += dot8(wv, xe + bl*HID + k);
      }
      PM[((size_t)(half*16+bl)*TE + t)*ATTD + a] = __float2bfloat16(acc);
    }
  }
}

// ================ persistent scan kernel (fast grid barrier) ================
__global__ __launch_bounds__(256) void k_scan(
    const bf16* __restrict__ XS, const bf16* __restrict__ PM,
    const float* __restrict__ enc, float* __restrict__ MEL,
    float* __restrict__ AH0, float* __restrict__ AH1, float* __restrict__ AC,
    float* __restrict__ DH0, float* __restrict__ DH1, float* __restrict__ DC,
    float* __restrict__ CTX0, float* __restrict__ CTX1,
    float* __restrict__ W, float* __restrict__ WC, float* __restrict__ E,
    int* __restrict__ arrive, int* __restrict__ go,
    const float* __restrict__ awih, const float* __restrict__ awhh,
    const float* __restrict__ abih, const float* __restrict__ abhh,
    const float* __restrict__ dwih, const float* __restrict__ dwhh,
    const float* __restrict__ dbih, const float* __restrict__ dbhh,
    const float* __restrict__ qw, const float* __restrict__ convw,
    const float* __restrict__ fcw, const float* __restrict__ vw,
    const float* __restrict__ projw)
{
  const int bid = blockIdx.x, tid = threadIdx.x;
  const int b = bid>>3, chunk = bid&7;   // phase B/C roles
  int nbar = 0;

  // ---- persistent LDS (loaded once) ----
  __shared__ __align__(16) float fcs[128*33];
  __shared__ __align__(16) float cw0[32*31], cw1[32*31];
  __shared__ float vv[128];
  // ---- per-step LDS ----
  __shared__ __align__(16) float wpad[632], wcpad[632];
  __shared__ float qs[128];
  __shared__ float convb[4][32];
  __shared__ __align__(16) float wl[600];
  __shared__ float ctxp[64][9];
  __shared__ float melp[10][16];
  __shared__ float red[4];
  __shared__ float sbc;

  for (int i=tid;i<128*33;i+=256){ int a=i/33,c=i-a*33; fcs[i]=(c<32)?fcw[a*32+c]:0.f; }
  for (int i=tid;i<32*31;i+=256){ int c=i/31,k=i-c*31; cw0[i]=convw[c*62+k]; cw1[i]=convw[c*62+31+k]; }
  if (tid<128) vv[tid]=vw[tid];
  __syncthreads();

  float* AHb[2]={AH0,AH1};
  float* DHb[2]={DH0,DH1};
  float* CTXb[2]={CTX0,CTX1};

  for (int t=0;t<=TD;t++){
    const int p=t&1, pp=1-p;
    const float* AHr = AHb[pp];  float* AHw = AHb[p];
    const float* CTXr= CTXb[pp]; float* CTXw= CTXb[p];

    // ================= phase A: lstmA(t) || lstmD(t-1) =================
    if (bid < 128){
      if (t < TD){
        const int ba=tid>>3, j=tid&7, c0=bid*4;
        const bf16* xs = XS + ((size_t)t*NB+ba)*PREN;
        const float* cx = CTXr + ba*HID;
        const float* hr = AHr + ba*HID;
        float acc[16];
        #pragma unroll
        for (int q=0;q<16;q++) acc[q]=0.f;
        for (int i=0;i<20;i++){
          int k8=i*64+j*8;
          float z[8];
          if (k8<256) ld8bf(xs+k8,z);
          else ld8f((k8<768)? cx+(k8-256) : hr+(k8-768), z);
          #pragma unroll
          for (int cc=0;cc<4;cc++){
            #pragma unroll
            for (int g=0;g<4;g++){
              int row=g*HID+c0+cc;
              const float* wp=(k8<768)? awih+(size_t)row*768+k8
                                      : awhh+(size_t)row*HID+(k8-768);
              float wv[8]; ld8f(wp,wv);
              acc[cc*4+g]+=dot8(wv,z);
            }
          }
        }
        #pragma unroll
        for (int q=0;q<16;q++){
          acc[q]+=__shfl_xor(acc[q],1);
          acc[q]+=__shfl_xor(acc[q],2);
          acc[q]+=__shfl_xor(acc[q],4);
        }
        if (j==0){
          #pragma unroll
          for (int cc=0;cc<4;cc++){
            int cell=c0+cc;
            float g0=acc[cc*4+0]+abih[cell]+abhh[cell];
            float g1=acc[cc*4+1]+abih[HID+cell]+abhh[HID+cell];
            float g2=acc[cc*4+2]+abih[2*HID+cell]+abhh[2*HID+cell];
            float g3=acc[cc*4+3]+abih[3*HID+cell]+abhh[3*HID+cell];
            float c2=sigm(g1)*AC[ba*HID+cell]+sigm(g0)*tanhfast(g2);
            AC[ba*HID+cell]=c2;
            AHw[ba*HID+cell]=sigm(g3)*tanhfast(c2);
          }
        }
      }
    } else if (t>=1){
      const int ba=tid>>3, j=tid&7, c0=(bid-128)*4;
      const float* ah = AHr + ba*HID;      // AH(t-1)
      const float* cx = CTXr + ba*HID;     // CTX(t-1)
      const float* dhr= DHb[p] + ba*HID;   // DH(t-2)
      float* DHw = DHb[pp];                // DH(t-1)
      float acc[16];
      #pragma unroll
      for (int q=0;q<16;q++) acc[q]=0.f;
      for (int i=0;i<24;i++){
        int k8=i*64+j*8;
        float z[8];
        ld8f((k8<512)? ah+k8 : (k8<1024)? cx+(k8-512) : dhr+(k8-1024), z);
        #pragma unroll
        for (int cc=0;cc<4;cc++){
          #pragma unroll
          for (int g=0;g<4;g++){
            int row=g*HID+c0+cc;
            const float* wp=(k8<1024)? dwih+(size_t)row*1024+k8
                                     : dwhh+(size_t)row*HID+(k8-1024);
            float wv[8]; ld8f(wp,wv);
            acc[cc*4+g]+=dot8(wv,z);
          }
        }
      }
      #pragma unroll
      for (int q=0;q<16;q++){
        acc[q]+=__shfl_xor(acc[q],1);
        acc[q]+=__shfl_xor(acc[q],2);
        acc[q]+=__shfl_xor(acc[q],4);
      }
      if (j==0){
        #pragma unroll
        for (int cc=0;cc<4;cc++){
          int cell=c0+cc;
          float g0=acc[cc*4+0]+dbih[cell]+dbhh[cell];
          float g1=acc[cc*4+1]+dbih[HID+cell]+dbhh[HID+cell];
          float g2=acc[cc*4+2]+dbih[2*HID+cell]+dbhh[2*HID+cell];
          float g3=acc[cc*4+3]+dbih[3*HID+cell]+dbhh[3*HID+cell];
          float c2=sigm(g1)*DC[ba*HID+cell]+sigm(g0)*tanhfast(g2);
          DC[ba*HID+cell]=c2;
          DHw[ba*HID+cell]=sigm(g3)*tanhfast(c2);
        }
      }
    }
    nbar++; gbar(arrive, go, nbar);

    // ================= phase B: mel(t-1) + q(t) + energies(t) ==========
    if (t>=1 && tid<160){
      int ol=tid>>4, ks=tid&15, k0=ks*64;
      const float* dh = DHb[pp] + b*HID;   // DH(t-1)
      const float* cx = CTXr + b*HID;      // CTX(t-1)
      const float* zp = (k0<512)? dh+k0 : cx+(k0-512);
      const float* pw = projw + (size_t)(chunk*10+ol)*1024 + k0;
      float a=0.f;
      #pragma unroll
      for (int k=0;k<64;k+=8){
        float wv[8],z[8]; ld8f(pw+k,wv); ld8f(zp+k,z);
        a+=dot8(wv,z);
      }
      melp[ol][ks]=a;
    }
    if (t<TD){
      if (tid<128){
        const float* qr=qw+(size_t)tid*HID;
        const float* ah=AHw + b*HID;       // AH(t)
        float acc=0.f;
        for (int k=0;k<HID;k+=8){
          float wv[8]; ld8f(qr+k,wv);
          acc += dot8(wv, ah+k);
        }
        qs[tid]=acc;
      }
      for (int i=tid;i<630;i+=256){
        wpad[i]  = (i>=15&&i<615)? W [(size_t)b*TE+i-15] : 0.f;
        wcpad[i] = (i>=15&&i<615)? WC[(size_t)b*TE+i-15] : 0.f;
      }
    }
    __syncthreads();
    if (t>=1 && tid<10){
      float s=0.f;
      #pragma unroll
      for (int k=0;k<16;k++) s+=melp[tid][k];
      MEL[((size_t)b*TD+(t-1))*TGT+chunk*10+tid]=s;
    }
    if (t==TD) break;   // after lstmD(599) + mel(599)
    {
      int wid=tid>>6, lane=tid&63, tbase=chunk*75;
      for (int it=0; it<19; it++){
        int off=it*4+wid; int te=tbase+off; bool act=(off<75);
        if (act&&lane<32){
          float s=0.f; int c=lane;
          for (int k=0;k<LK;k++)
            s+=cw0[c*31+k]*wpad[te+k]+cw1[c*31+k]*wcpad[te+k];
          convb[wid][c]=s;
        }
        __syncthreads();
        if (act){
          float part=0.f;
          #pragma unroll
          for (int half=0;half<2;half++){
            int a=lane+half*64;
            float loc=0.f;
            #pragma unroll
            for (int c=0;c<32;c++) loc+=fcs[a*33+c]*convb[wid][c];
            float x=qs[a]+b2f(PM[((size_t)b*TE+te)*ATTD+a])+loc;
            part+=vv[a]*tanhfast(x);
          }
          for (int o2=1;o2<64;o2<<=1) part+=__shfl_xor(part,o2);
          if (lane==0) E[(size_t)b*TE+te]=part;
        }
        __syncthreads();
      }
    }
    nbar++; gbar(arrive, go, nbar);

    // ================= phase C: softmax(b) + ctx slice =================
    {
      const int hc=chunk;
      float e0[3]; float mx=-1e30f;
      #pragma unroll
      for (int r=0;r<3;r++){
        int i=tid+r*256;
        float v=(i<TE)? E[(size_t)b*TE+i] : -1e30f;
        e0[r]=v; mx=fmaxf(mx,v);
      }
      for (int o2=1;o2<64;o2<<=1) mx=fmaxf(mx,__shfl_xor(mx,o2));
      if ((tid&63)==0) red[tid>>6]=mx;
      __syncthreads();
      if (tid==0) sbc=fmaxf(fmaxf(red[0],red[1]),fmaxf(red[2],red[3]));
      __syncthreads();
      float m=sbc;
      float ex[3], s=0.f;
      #pragma unroll
      for (int r=0;r<3;r++){
        int i=tid+r*256;
        ex[r]=(i<TE)? __expf(e0[r]-m) : 0.f;
        s+=ex[r];
      }
      for (int o2=1;o2<64;o2<<=1) s+=__shfl_xor(s,o2);
      __syncthreads();
      if ((tid&63)==0) red[tid>>6]=s;
      __syncthreads();
      if (tid==0) sbc=red[0]+red[1]+red[2]+red[3];
      __syncthreads();
      float inv=1.f/sbc;
      #pragma unroll
      for (int r=0;r<3;r++){
        int i=tid+r*256;
        if (i<TE){
          float w2=ex[r]*inv;
          wl[i]=w2;
          if (hc==0){ W[(size_t)b*TE+i]=w2; WC[(size_t)b*TE+i]+=w2; }
        }
      }
      __syncthreads();
      int hl2=tid&31, ts=tid>>5;
      int h=hc*64+hl2*2;
      const float* ep = enc + (size_t)b*TE*HID + h;
      float a0=0.f,a1=0.f;
      for (int tt=ts*75; tt<ts*75+75; tt++){
        float2 u=*(const float2*)(ep+(size_t)tt*HID);
        float w2=wl[tt]; a0+=w2*u.x; a1+=w2*u.y;
      }
      ctxp[hl2*2][ts]=a0; ctxp[hl2*2+1][ts]=a1;
      __syncthreads();
      if (tid<64){
        float s2=0.f;
        #pragma unroll
        for (int k=0;k<8;k++) s2+=ctxp[tid][k];
        CTXw[(size_t)b*HID+hc*64+tid]=s2;
      }
    }
    nbar++; gbar(arrive, go, nbar);
  }
}

// ---------------- postnet conv (generic, bf16 internal activations) --------
__global__ __launch_bounds__(256) void k_conv(
    const void* __restrict__ inv_, bf16* __restrict__ out,
    const float* __restrict__ w, const float* __restrict__ bias,
    int IC, int OC, int mel_in, int do_tanh, int b0)
{
  __shared__ __align__(16) float xs[256*36];
  int bl=blockIdx.x, bg=b0+bl, oct=blockIdx.y, t0=blockIdx.z*32, tid=threadIdx.x;
  int oc = oct*256 + tid;
  float acc[32];
  #pragma unroll
  for (int q=0;q<32;q++) acc[q]=0.f;
  int nch=(IC+255)/256;
  const float* inf_ = (const float*)inv_;
  const bf16*  inb_ = (const bf16*)inv_;
  for (int ch=0;ch<nch;ch++){
    int icb=ch*256, icn=min(256,IC-icb);
    __syncthreads();
    for (int i=tid;i<icn*36;i+=256){
      int icl=i/36, tt=i-icl*36;
      int tg=t0+tt-2;
      float v=0.f;
      if (tg>=0 && tg<TD){
        int ic=icb+icl;
        v = mel_in ? inf_[((size_t)bg*TD+tg)*TGT+ic]
                   : b2f(inb_[((size_t)bl*IC+ic)*TD+tg]);
      }
      xs[i]=v;
    }
    __syncthreads();
    if (oc<OC){
      const float* wp = w + ((size_t)oc*IC+icb)*5;
      for (int ic=0;ic<icn;ic++){
        float xw[36];
        #pragma unroll
        for (int q=0;q<9;q++) ((float4*)xw)[q]=((const float4*)(xs+ic*36))[q];
        float wk0=wp[ic*5  ],wk1=wp[ic*5+1],wk2=wp[ic*5+2],
              wk3=wp[ic*5+3],wk4=wp[ic*5+4];
        #pragma unroll
        for (int tt=0;tt<32;tt++)
          acc[tt] += wk0*xw[tt]+wk1*xw[tt+1]+wk2*xw[tt+2]+wk3*xw[tt+3]+wk4*xw[tt+4];
      }
    }
  }
  if (oc<OC){
    float bv=bias[oc];
    for (int tt=0;tt<32;tt++){
      int tg=t0+tt;
      if (tg<TD){
        float v=acc[tt]+bv;
        if (do_tanh) v=tanhfast(v);
        out[((size_t)bl*OC+oc)*TD+tg]=__float2bfloat16(v);
      }
    }
  }
}

// ---------------- postnet last layer + in-place residual on d_out ----------
__global__ __launch_bounds__(256) void k_conv_last(
    const bf16* __restrict__ in, const float* __restrict__ w,
    const float* __restrict__ bias, float* __restrict__ outp, int b0)
{
  __shared__ __align__(16) float xs[256*36];
  int bl=blockIdx.x, bg=b0+bl, t0=blockIdx.z*32, tid=threadIdx.x;
  int oc = tid;
  float acc[32];
  #pragma unroll
  for (int q=0;q<32;q++) acc[q]=0.f;
  for (int ch=0;ch<2;ch++){
    int icb=ch*256;
    __syncthreads();
    for (int i=tid;i<256*36;i+=256){
      int icl=i/36, tt=i-icl*36;
      int tg=t0+tt-2;
      float v=0.f;
      if (tg>=0 && tg<TD){
        int ic=icb+icl;
        v = b2f(in[((size_t)bl*PH+ic)*TD+tg]);
      }
      xs[i]=v;
    }
    __syncthreads();
    if (oc<TGT){
      const float* wp = w + ((size_t)oc*PH+icb)*5;
      for (int ic=0;ic<256;ic++){
        float xw[36];
        #pragma unroll
        for (int q=0;q<9;q++) ((float4*)xw)[q]=((const float4*)(xs+ic*36))[q];
        float wk0=wp[ic*5  ],wk1=wp[ic*5+1],wk2=wp[ic*5+2],
              wk3=wp[ic*5+3],wk4=wp[ic*5+4];
        #pragma unroll
        for (int tt=0;tt<32;tt++)
          acc[tt] += wk0*xw[tt]+wk1*xw[tt+1]+wk2*xw[tt+2]+wk3*xw[tt+3]+wk4*xw[tt+4];
      }
    }
  }
  if (oc<TGT){
    float bv=bias[oc];
    for (int tt=0;tt<32;tt++){
      int tg=t0+tt;
      if (tg<TD){
        size_t idx=((size_t)bg*TD+tg)*TGT+oc;
        outp[idx]=acc[tt]+bv+outp[idx];
      }
    }
  }
}

extern "C" void kernel_launch(void* const* d_in, const int* in_sizes, int n_in,
                              void* d_out, int out_size, void* d_ws, size_t ws_size,
                              hipStream_t stream)
{
  const float* enc =(const float*)d_in[0];
  const float* dec =(const float*)d_in[1];
  const float* pw1 =(const float*)d_in[2];  const float* pb1=(const float*)d_in[3];
  const float* pw2 =(const float*)d_in[4];  const float* pb2=(const float*)d_in[5];
  const float* awih=(const float*)d_in[6];  const float* awhh=(const float*)d_in[7];
  const float* abih=(const float*)d_in[8];  const float* abhh=(const float*)d_in[9];
  const float* dwih=(const float*)d_in[10]; const float* dwhh=(const float*)d_in[11];
  const float* dbih=(const float*)d_in[12]; const float* dbhh=(const float*)d_in[13];
  const float* memw=(const float*)d_in[14]; const float* memb=(const float*)d_in[15];
  const float* qw  =(const float*)d_in[16];
  const float* lcw =(const float*)d_in[17];
  const float* lfw =(const float*)d_in[18];
  const float* vw  =(const float*)d_in[19];
  const float* pjw =(const float*)d_in[20];
  const float* cwt0=(const float*)d_in[21]; const float* cbt0=(const float*)d_in[22];
  const float* cwt1=(const float*)d_in[23]; const float* cbt1=(const float*)d_in[24];
  const float* cwt2=(const float*)d_in[25]; const float* cbt2=(const float*)d_in[26];
  const float* cwt3=(const float*)d_in[27]; const float* cbt3=(const float*)d_in[28];
  const float* cwt4=(const float*)d_in[29]; const float* cbt4=(const float*)d_in[30];
  float* MEL = (float*)d_out;
  (void)in_sizes; (void)n_in; (void)out_size; (void)ws_size;

  char* base=(char*)d_ws;
  const size_t XS_B = (size_t)TD*NB*PREN*2;   //  9,830,400 B
  const size_t PM_B = (size_t)NB*TE*ATTD*2;   //  4,915,200 B
  const size_t HB   = (size_t)NB*HID*4;       //     65,536 B
  const size_t WB   = (size_t)NB*TE*4;        //     76,800 B
  bf16* XSb = (bf16*)base;
  bf16* PMb = (bf16*)(base + XS_B);
  char* sbase = base + XS_B + PM_B;
  float* AH0 =(float*)(sbase+0*HB);
  float* AH1 =(float*)(sbase+1*HB);
  float* ACb =(float*)(sbase+2*HB);
  float* DH0 =(float*)(sbase+3*HB);
  float* DH1 =(float*)(sbase+4*HB);
  float* DCb =(float*)(sbase+5*HB);
  float* CTX0=(float*)(sbase+6*HB);
  float* CTX1=(float*)(sbase+7*HB);
  float* Wb  =(float*)(sbase+8*HB);
  float* WCb =(float*)(sbase+8*HB+WB);
  float* Eb  =(float*)(sbase+8*HB+2*WB);
  int*   arrive=(int*)(sbase+8*HB+3*WB);              // 256 slots x 64B
  int*   go    =(int*)(sbase+8*HB+3*WB+256*64);
  const size_t BAR_B = 256*64 + 64;
  const int G = 8;
  const size_t PBc_B = (size_t)G*PH*TD*2;     //  4,915,200 B
  bf16* PB0 = (bf16*)base;
  bf16* PB1 = (bf16*)(base + PBc_B);

  hipMemsetAsync(sbase, 0, 8*HB+3*WB+BAR_B, stream);

  k_prenet<<<TD,256,0,stream>>>(dec,pw1,pb1,pw2,pb2,XSb);
  k_procmem<<<TE,256,0,stream>>>(enc,memw,memb,PMb);

  k_scan<<<256,256,0,stream>>>(XSb,PMb,enc,MEL,
      AH0,AH1,ACb,DH0,DH1,DCb,CTX0,CTX1,Wb,WCb,Eb,arrive,go,
      awih,awhh,abih,abhh,dwih,dwhh,dbih,dbhh,
      qw,lcw,lfw,vw,pjw);

  for (int c=0;c<NB/G;c++){
    int b0=c*G;
    k_conv<<<dim3(G,2,19),256,0,stream>>>(MEL,PB0,cwt0,cbt0,TGT,PH,1,1,b0);
    k_conv<<<dim3(G,2,19),256,0,stream>>>(PB0,PB1,cwt1,cbt1,PH,PH,0,1,b0);
    k_conv<<<dim3(G,2,19),256,0,stream>>>(PB1,PB0,cwt2,cbt2,PH,PH,0,1,b0);
    k_conv<<<dim3(G,2,19),256,0,stream>>>(PB0,PB1,cwt3,cbt3,PH,PH,0,1,b0);
    k_conv_last<<<dim3(G,1,19),256,0,stream>>>(PB1,cwt4,cbt4,MEL,b0);
  }
}